// Round 12
// baseline (267.115 us; speedup 1.0000x reference)
//
#include <hip/hip_runtime.h>
#include <hip/hip_bf16.h>
#include <math.h>

#define DIM_  1536
#define NH_   12
#define HD_   128
#define S_    2048
#define B_    2
#define M_    (B_*S_)       /* 4096 rows */
#define WEL_  (DIM_*DIM_)   /* 2359296 */

typedef __attribute__((ext_vector_type(8))) _Float16 f16x8;
typedef __attribute__((ext_vector_type(4))) short short4v;
typedef __attribute__((ext_vector_type(8))) short short8v;
typedef __attribute__((ext_vector_type(4))) float f32x4;

#define SSCALE_LOG2E (0.08838834764831845f * 1.4426950408889634f)

static __device__ __forceinline__ short f2h(float f) {
  union { _Float16 h; short s; } u;
  u.h = (_Float16)f;
  return u.s;
}

static __device__ __forceinline__ unsigned pk2h(float a, float b) {
  typedef __attribute__((ext_vector_type(2))) __fp16 fp16x2;
  union { fp16x2 v; unsigned u; } u2;
  u2.v = __builtin_amdgcn_cvt_pkrtz(a, b);
  return u2.u;
}

// ---------------------------------------------------------------------------
// Fused convert: x + wq/wk/wv/wo -> fp16. 1966080 chunks of 8.
// ---------------------------------------------------------------------------
__global__ __launch_bounds__(256) void f2h5_k(
    const float* __restrict__ x, const float* __restrict__ wq,
    const float* __restrict__ wk, const float* __restrict__ wv,
    const float* __restrict__ wo,
    short* __restrict__ x16, short* __restrict__ w16, short* __restrict__ wo16)
{
  int i = blockIdx.x * 256 + threadIdx.x;
  const float* src; short* dst; int j;
  if (i < 786432)       { src = x;  dst = x16;            j = i; }
  else if (i < 1081344) { src = wq; dst = w16;            j = i - 786432; }
  else if (i < 1376256) { src = wk; dst = w16 + WEL_;     j = i - 1081344; }
  else if (i < 1671168) { src = wv; dst = w16 + 2 * WEL_; j = i - 1376256; }
  else                  { src = wo; dst = wo16;           j = i - 1671168; }
  const float4* p = (const float4*)src + (size_t)j * 2;
  float4 a = p[0], b = p[1];
  short8v o;
  o[0] = f2h(a.x); o[1] = f2h(a.y); o[2] = f2h(a.z); o[3] = f2h(a.w);
  o[4] = f2h(b.x); o[5] = f2h(b.y); o[6] = f2h(b.z); o[7] = f2h(b.w);
  *((short8v*)dst + j) = o;
}

// ---------------------------------------------------------------------------
// MFMA fp16 GEMM core, double-buffered LDS, ONE barrier per K-step,
// STAGE issued at phase top (drain overlaps frag-reads + MFMA).
// 128x128 tile, BK=32, 4 waves. Pre-swizzled global sources.
// MODE 0: fp16 row-major out. MODE 2: transposed V out vt[bh*HD+d][s].
// ---------------------------------------------------------------------------
template<int MODE>
static __device__ __forceinline__ void gemm16_core(
    const short* __restrict__ A16, const short* __restrict__ W16,
    const float* __restrict__ bias, short* __restrict__ Outp,
    int m0, int n0, char* __restrict__ Ab, char* __restrict__ Bb)
{
  const int tid = threadIdx.x;
  const int l  = tid & 63, w = tid >> 6;
  const int wr = w >> 1, wc = w & 1;
  const int lc = l & 15, lg = l >> 4;

  f32x4 acc[4][4] = {};

  const int rs  = w * 16 + (l >> 2);
  const int gsl = ((l & 3) ^ ((rs >> 1) & 3)) * 8;
  const short* gA0 = A16 + (size_t)(m0 + rs) * DIM_ + gsl;
  const short* gA1 = A16 + (size_t)(m0 + 64 + rs) * DIM_ + gsl;
  const short* gB0 = W16 + (size_t)(n0 + rs) * DIM_ + gsl;
  const short* gB1 = W16 + (size_t)(n0 + 64 + rs) * DIM_ + gsl;

#define GSTAGE(buf, k0)                                                        \
  {                                                                            \
    __builtin_amdgcn_global_load_lds(                                          \
        (const __attribute__((address_space(1))) unsigned*)(gA0 + (k0)),       \
        (__attribute__((address_space(3))) unsigned*)(Ab + (buf) * 8192 + w * 1024), 16, 0, 0); \
    __builtin_amdgcn_global_load_lds(                                          \
        (const __attribute__((address_space(1))) unsigned*)(gA1 + (k0)),       \
        (__attribute__((address_space(3))) unsigned*)(Ab + (buf) * 8192 + 4096 + w * 1024), 16, 0, 0); \
    __builtin_amdgcn_global_load_lds(                                          \
        (const __attribute__((address_space(1))) unsigned*)(gB0 + (k0)),       \
        (__attribute__((address_space(3))) unsigned*)(Bb + (buf) * 8192 + w * 1024), 16, 0, 0); \
    __builtin_amdgcn_global_load_lds(                                          \
        (const __attribute__((address_space(1))) unsigned*)(gB1 + (k0)),       \
        (__attribute__((address_space(3))) unsigned*)(Bb + (buf) * 8192 + 4096 + w * 1024), 16, 0, 0); \
  }

  GSTAGE(0, 0);
  __syncthreads();                       // buf0 ready
  int cur = 0;
  for (int k0 = 0; k0 < DIM_; k0 += 32) {
    if (k0 + 32 < DIM_) GSTAGE(cur ^ 1, k0 + 32);   // issue first: max overlap
    const char* Ac = Ab + cur * 8192;
    const char* Bc = Bb + cur * 8192;
    f16x8 af[4], bf[4];
#pragma unroll
    for (int mt = 0; mt < 4; ++mt) {
      int ar = wr * 64 + mt * 16 + lc;
      af[mt] = *(const f16x8*)(Ac + ar * 64 + ((lg ^ ((ar >> 1) & 3)) << 4));
    }
#pragma unroll
    for (int nt = 0; nt < 4; ++nt) {
      int br = wc * 64 + nt * 16 + lc;
      bf[nt] = *(const f16x8*)(Bc + br * 64 + ((lg ^ ((br >> 1) & 3)) << 4));
    }
    __builtin_amdgcn_s_setprio(1);
#pragma unroll
    for (int mt = 0; mt < 4; ++mt)
#pragma unroll
      for (int nt = 0; nt < 4; ++nt)
        acc[mt][nt] = __builtin_amdgcn_mfma_f32_16x16x32_f16(af[mt], bf[nt], acc[mt][nt], 0, 0, 0);
    __builtin_amdgcn_s_setprio(0);
    __syncthreads();                     // next buf ready; cur reads all done
    cur ^= 1;
  }
#undef GSTAGE

  if (MODE == 0) {
#pragma unroll
    for (int nt = 0; nt < 4; ++nt) {
      int col = n0 + wc * 64 + nt * 16 + lc;
      float bb = bias[col];
#pragma unroll
      for (int mt = 0; mt < 4; ++mt) {
#pragma unroll
        for (int r = 0; r < 4; ++r) {
          int rowm = m0 + wr * 64 + mt * 16 + lg * 4 + r;
          Outp[(size_t)rowm * DIM_ + col] = f2h(acc[mt][nt][r] + bb);
        }
      }
    }
  } else {
#pragma unroll
    for (int nt = 0; nt < 4; ++nt) {
      int colg = n0 + wc * 64 + nt * 16 + lc;
      int h = colg >> 7, d = colg & 127;
      float bb = bias[colg];
#pragma unroll
      for (int mt = 0; mt < 4; ++mt) {
        int rowg = m0 + wr * 64 + mt * 16 + lg * 4;
        int b = rowg >> 11, s = rowg & (S_ - 1);
        short4v o4;
#pragma unroll
        for (int r = 0; r < 4; ++r) o4[r] = f2h(acc[mt][nt][r] + bb);
        *(short4v*)(Outp + ((size_t)((b * NH_ + h) * HD_ + d)) * S_ + s) = o4;
      }
    }
  }
}

// 1-D grid 1152 = 8 XCD-chunks of 144; logical order n-fastest, then m, then z.
__global__ __launch_bounds__(256) void gemm_qkv16_k(
    const short* __restrict__ x16, const short* __restrict__ w16,
    const float* __restrict__ bq, const float* __restrict__ bk,
    const float* __restrict__ bv,
    short* __restrict__ q16, short* __restrict__ k16, short* __restrict__ vt)
{
  __shared__ __align__(16) char Ab[2][8192];
  __shared__ __align__(16) char Bb[2][8192];
  const int bid = blockIdx.x;
  const int wrk = (bid & 7) * 144 + (bid >> 3);   // XCD-chunked
  const int n   = wrk % 12;
  const int m   = (wrk / 12) % 32;
  const int z   = wrk / 384;
  if (z == 2)
    gemm16_core<2>(x16, w16 + 2 * (size_t)WEL_, bv, vt,
                   m * 128, n * 128, &Ab[0][0], &Bb[0][0]);
  else
    gemm16_core<0>(x16, w16 + (size_t)z * WEL_, z ? bk : bq, z ? k16 : q16,
                   m * 128, n * 128, &Ab[0][0], &Bb[0][0]);
}

// ---------------------------------------------------------------------------
// gemm_out: 128x64 tile, dbuf, one barrier/step, stage-first, fp32 out.
// 1-D grid 768 = 8 chunks of 96; logical n-fastest (24), then m (32).
// ---------------------------------------------------------------------------
__global__ __launch_bounds__(256) void gemm_out64_k(
    const short* __restrict__ att16, const short* __restrict__ wo16,
    const float* __restrict__ bo, float* __restrict__ out)
{
  __shared__ __align__(16) char Ab[2][8192];
  __shared__ __align__(16) char Bb[2][4096];
  const int bid = blockIdx.x;
  const int wrk = (bid & 7) * 96 + (bid >> 3);
  const int m0 = (wrk / 24) * 128, n0 = (wrk % 24) * 64;
  const int tid = threadIdx.x;
  const int l  = tid & 63, w = tid >> 6;
  const int lc = l & 15, lg = l >> 4;

  f32x4 acc[2][4] = {};

  const int rsA = w * 32 + (l >> 2);
  const int rsB = w * 16 + (l >> 2);
  const int gslA = ((l & 3) ^ ((rsA >> 1) & 3)) * 8;
  const int gslB = ((l & 3) ^ ((rsB >> 1) & 3)) * 8;
  const short* gA0 = att16 + (size_t)(m0 + rsA) * DIM_ + gslA;
  const short* gA1 = att16 + (size_t)(m0 + 16 + rsA) * DIM_ + gslA;
  const short* gB0 = wo16 + (size_t)(n0 + rsB) * DIM_ + gslB;

#define GSTAGE(buf, k0)                                                        \
  {                                                                            \
    __builtin_amdgcn_global_load_lds(                                          \
        (const __attribute__((address_space(1))) unsigned*)(gA0 + (k0)),       \
        (__attribute__((address_space(3))) unsigned*)(&Ab[buf][0] + w * 2048), 16, 0, 0); \
    __builtin_amdgcn_global_load_lds(                                          \
        (const __attribute__((address_space(1))) unsigned*)(gA1 + (k0)),       \
        (__attribute__((address_space(3))) unsigned*)(&Ab[buf][0] + w * 2048 + 1024), 16, 0, 0); \
    __builtin_amdgcn_global_load_lds(                                          \
        (const __attribute__((address_space(1))) unsigned*)(gB0 + (k0)),       \
        (__attribute__((address_space(3))) unsigned*)(&Bb[buf][0] + w * 1024), 16, 0, 0); \
  }

  GSTAGE(0, 0);
  __syncthreads();
  int cur = 0;
  for (int k0 = 0; k0 < DIM_; k0 += 32) {
    if (k0 + 32 < DIM_) GSTAGE(cur ^ 1, k0 + 32);
    const char* Ac = &Ab[cur][0];
    const char* Bc = &Bb[cur][0];
    f16x8 af[2], bf[4];
#pragma unroll
    for (int mt = 0; mt < 2; ++mt) {
      int ar = w * 32 + mt * 16 + lc;
      af[mt] = *(const f16x8*)(Ac + ar * 64 + ((lg ^ ((ar >> 1) & 3)) << 4));
    }
#pragma unroll
    for (int nt = 0; nt < 4; ++nt) {
      int br = nt * 16 + lc;
      bf[nt] = *(const f16x8*)(Bc + br * 64 + ((lg ^ ((br >> 1) & 3)) << 4));
    }
    __builtin_amdgcn_s_setprio(1);
#pragma unroll
    for (int mt = 0; mt < 2; ++mt)
#pragma unroll
      for (int nt = 0; nt < 4; ++nt)
        acc[mt][nt] = __builtin_amdgcn_mfma_f32_16x16x32_f16(af[mt], bf[nt], acc[mt][nt], 0, 0, 0);
    __builtin_amdgcn_s_setprio(0);
    __syncthreads();
    cur ^= 1;
  }
#undef GSTAGE

#pragma unroll
  for (int nt = 0; nt < 4; ++nt) {
    int col = n0 + nt * 16 + lc;
    float bb = bo[col];
#pragma unroll
    for (int mt = 0; mt < 2; ++mt) {
#pragma unroll
      for (int r = 0; r < 4; ++r) {
        int rowm = m0 + w * 32 + mt * 16 + lg * 4 + r;
        out[(size_t)rowm * DIM_ + col] = acc[mt][nt][r] + bb;
      }
    }
  }
}

// ---------------------------------------------------------------------------
// RMSNorm + grid RoPE, fp16 in -> fp16 head-major; q (z=0) and k (z=1) in one
// dispatch; q gets sscale*log2e folded in.
// ---------------------------------------------------------------------------
__global__ __launch_bounds__(256) void rms_rope_qk_k(
    const short* __restrict__ q16, const short* __restrict__ k16,
    const float* __restrict__ nq, const float* __restrict__ nk,
    const float* __restrict__ cf, const float* __restrict__ sf,
    const float* __restrict__ ch, const float* __restrict__ sh,
    const float* __restrict__ cw, const float* __restrict__ sw,
    short* __restrict__ qh, short* __restrict__ kh)
{
  const int z   = blockIdx.y;
  const short* t = z ? k16 : q16;
  const float* w = z ? nk : nq;
  short* outb   = z ? kh : qh;
  const float qsc0 = z ? 1.0f : SSCALE_LOG2E;

  const int row = blockIdx.x;
  const int b   = row >> 11;
  const int s   = row & (S_ - 1);
  const _Float16* rp = (const _Float16*)(t + (size_t)row * DIM_);

  float ss = 0.f;
  for (int i = threadIdx.x; i < DIM_; i += 256) {
    float v2 = (float)rp[i]; ss += v2 * v2;
  }
#pragma unroll
  for (int off = 32; off > 0; off >>= 1) ss += __shfl_down(ss, off);
  __shared__ float red[4];
  if ((threadIdx.x & 63) == 0) red[threadIdx.x >> 6] = ss;
  __syncthreads();
  float scale = rsqrtf((red[0] + red[1] + red[2] + red[3]) * (1.f / DIM_) + 1e-6f) * qsc0;

  const int fi = s >> 8;
  const int hi = (s >> 4) & 15;
  const int wi = s & 15;

  for (int p = threadIdx.x; p < NH_ * 64; p += 256) {
    int n = p >> 6, c = p & 63;
    float co, si;
    if (c < 22)      { co = cf[fi * 22 + c];        si = sf[fi * 22 + c]; }
    else if (c < 43) { co = ch[hi * 21 + (c - 22)]; si = sh[hi * 21 + (c - 22)]; }
    else             { co = cw[wi * 21 + (c - 43)]; si = sw[wi * 21 + (c - 43)]; }
    int d0 = n * HD_ + 2 * c;
    float xr = (float)rp[d0]     * scale * w[d0];
    float xi = (float)rp[d0 + 1] * scale * w[d0 + 1];
    float rr = xr * co - xi * si;
    float ri = xr * si + xi * co;
    *(unsigned int*)(outb + (((size_t)(b * NH_ + n) * S_ + s) * HD_ + 2 * c)) = pk2h(rr, ri);
  }
}

// ---------------------------------------------------------------------------
// fp16 MFMA flash attention v5 + XCD-chunked block swizzle.
// 1-D grid 768 = 8 chunks of 96; logical qtile-fastest (32), then bh (24)
// -> each XCD chunk = 3 consecutive heads' K/V resident in its L2.
// ---------------------------------------------------------------------------
__global__ __launch_bounds__(256) void attn_mfma5_k(
    const short* __restrict__ qb, const short* __restrict__ kb,
    const short* __restrict__ vtb, const int* __restrict__ seq_lens,
    short* __restrict__ o16)
{
  const int bid = blockIdx.x;
  const int wrk = (bid & 7) * 96 + (bid >> 3);
  const int bh  = wrk / 32;
  const int b   = bh / NH_;
  const int h   = bh - b * NH_;
  const int q0  = (wrk % 32) << 6;
  const int kvlen = seq_lens[b];
  const int tid  = threadIdx.x;
  const int wid  = tid >> 6;
  const int lane = tid & 63;
  const int lg   = lane >> 4;
  const int lc   = lane & 15;
  const int xo   = (lc & 7) << 4;

  __shared__ __align__(16) char Kt[16384];
  __shared__ __align__(16) char Vt[16384];
  __shared__ __align__(16) char Pt[4][2048];

  f16x8 bq[4];
  {
    const size_t base = ((size_t)bh * S_ + q0 + wid * 16 + lc) * HD_;
#pragma unroll
    for (int dc = 0; dc < 4; ++dc)
      bq[dc] = *(const f16x8*)(qb + base + dc * 32 + lg * 8);
  }

  const short* kgA = kb + ((size_t)bh * S_ + wid * 16 + lg) * HD_
                        + ((lc * 8) ^ (lg << 3));
  const short* kgB = kb + ((size_t)bh * S_ + wid * 16 + 4 + lg) * HD_
                        + ((lc * 8) ^ ((lg ^ 4) << 3));
  const short* vg  = vtb + ((size_t)bh * HD_ + wid * 32 + (lane >> 3)) * S_
                         + (((lane & 7) * 8) ^ ((lane >> 3) << 3));

#define STAGE_K()                                                              \
  {                                                                            \
    _Pragma("unroll")                                                          \
    for (int j = 0; j < 4; ++j) {                                              \
      const short* g = (j & 1) ? (kgB + ((j - 1) >> 1) * (8 * HD_))            \
                               : (kgA + (j >> 1) * (8 * HD_));                 \
      __builtin_amdgcn_global_load_lds(                                        \
          (const __attribute__((address_space(1))) unsigned*)g,                \
          (__attribute__((address_space(3))) unsigned*)(Kt + (wid * 16 + j * 4) * 256), \
          16, 0, 0);                                                           \
    }                                                                          \
  }
#define STAGE_V()                                                              \
  {                                                                            \
    _Pragma("unroll")                                                          \
    for (int j = 0; j < 4; ++j) {                                              \
      __builtin_amdgcn_global_load_lds(                                        \
          (const __attribute__((address_space(1))) unsigned*)(vg + j * 8 * S_),\
          (__attribute__((address_space(3))) unsigned*)(Vt + (wid * 32 + j * 8) * 128), \
          16, 0, 0);                                                           \
    }                                                                          \
  }

  f32x4 oacc[8] = {};
  float m = -3.0e38f, l = 0.f;

  const int nt = kvlen >> 6;

  STAGE_K();
  kgA += 64 * HD_; kgB += 64 * HD_;
  __syncthreads();

  for (int ti = 0; ti < nt; ++ti) {
    STAGE_V();
    vg += 64;

    f32x4 s[4];
    __builtin_amdgcn_s_setprio(1);
#pragma unroll
    for (int kt = 0; kt < 4; ++kt) {
      f32x4 a = {0.f, 0.f, 0.f, 0.f};
      const char* kr = Kt + (kt * 16 + lc) * 256;
#pragma unroll
      for (int dc = 0; dc < 4; ++dc) {
        f16x8 kf = *(const f16x8*)(kr + ((dc * 64 + lg * 16) ^ xo));
        a = __builtin_amdgcn_mfma_f32_16x16x32_f16(kf, bq[dc], a, 0, 0, 0);
      }
      s[kt] = a;
    }
    __builtin_amdgcn_s_setprio(0);

    float t0 = -3.0e38f;
#pragma unroll
    for (int kt = 0; kt < 4; ++kt)
#pragma unroll
      for (int r = 0; r < 4; ++r) t0 = fmaxf(t0, s[kt][r]);
    t0 = fmaxf(t0, __shfl_xor(t0, 16));
    t0 = fmaxf(t0, __shfl_xor(t0, 32));

    if (__any(t0 > m + 8.f)) {
      float mn = fmaxf(m, t0);
      float a  = exp2f(m - mn);
      m = mn; l *= a;
#pragma unroll
      for (int r = 0; r < 4; ++r) {
        float ar = __shfl(a, 4 * lg + r);
#pragma unroll
        for (int n = 0; n < 8; ++n) oacc[n][r] *= ar;
      }
    }
    float ls = 0.f;
#pragma unroll
    for (int kt = 0; kt < 4; ++kt)
#pragma unroll
      for (int r = 0; r < 4; ++r) {
        float p = exp2f(s[kt][r] - m); s[kt][r] = p; ls += p;
      }
    ls += __shfl_xor(ls, 16);
    ls += __shfl_xor(ls, 32);
    l += ls;

    {
      char* pr = Pt[wid] + lc * 128;
#pragma unroll
      for (int kt = 0; kt < 4; ++kt) {
#pragma unroll
        for (int rr = 0; rr < 2; ++rr) {
          unsigned u = pk2h(s[kt][2 * rr], s[kt][2 * rr + 1]);
          int off = (kt * 32 + lg * 8 + rr * 4) ^ xo;
          *(unsigned*)(pr + off) = u;
        }
      }
    }

    __syncthreads();

    if (ti + 1 < nt) {
      STAGE_K();
      kgA += 64 * HD_; kgB += 64 * HD_;
    }

    __builtin_amdgcn_s_setprio(1);
#pragma unroll
    for (int kc = 0; kc < 2; ++kc) {
      f16x8 pa = *(const f16x8*)(Pt[wid] + lc * 128 + ((kc * 64 + lg * 16) ^ xo));
#pragma unroll
      for (int n = 0; n < 8; ++n) {
        f16x8 vf = *(const f16x8*)(Vt + (n * 16 + lc) * 128 + ((kc * 64 + lg * 16) ^ xo));
        oacc[n] = __builtin_amdgcn_mfma_f32_16x16x32_f16(pa, vf, oacc[n], 0, 0, 0);
      }
    }
    __builtin_amdgcn_s_setprio(0);

    __syncthreads();
  }

#pragma unroll
  for (int r = 0; r < 4; ++r) {
    float li = 1.f / __shfl(l, 4 * lg + r);
    int qrow = q0 + wid * 16 + 4 * lg + r;
#pragma unroll
    for (int n = 0; n < 8; ++n)
      o16[((size_t)(b * S_ + qrow) * NH_ + h) * HD_ + n * 16 + lc] = f2h(oacc[n][r] * li);
  }
#undef STAGE_K
#undef STAGE_V
}

// ---------------------------------------------------------------------------
// Workspace (94.4 MB, all fp16):
//  x16 | w16(3) | wo16 | q16(->att16) | k16 | vt | qh | kh
// ---------------------------------------------------------------------------
extern "C" void kernel_launch(void* const* d_in, const int* in_sizes, int n_in,
                              void* d_out, int out_size, void* d_ws, size_t ws_size,
                              hipStream_t stream) {
  const float* x        = (const float*)d_in[0];
  const int*   seq_lens = (const int*)d_in[1];
  const float* wq = (const float*)d_in[5];
  const float* bq = (const float*)d_in[6];
  const float* wk = (const float*)d_in[7];
  const float* bk = (const float*)d_in[8];
  const float* wv = (const float*)d_in[9];
  const float* bv = (const float*)d_in[10];
  const float* wo = (const float*)d_in[11];
  const float* bo = (const float*)d_in[12];
  const float* nq = (const float*)d_in[13];
  const float* nk = (const float*)d_in[14];
  const float* cf = (const float*)d_in[15];
  const float* sf = (const float*)d_in[16];
  const float* ch = (const float*)d_in[17];
  const float* sh = (const float*)d_in[18];
  const float* cw = (const float*)d_in[19];
  const float* sw = (const float*)d_in[20];

  const size_t rowelems = (size_t)M_ * DIM_;          // 6291456
  short* x16  = (short*)d_ws;
  short* w16  = x16 + rowelems;                       // 3*WEL_
  short* wo16 = w16 + 3 * (size_t)WEL_;
  short* q16  = wo16 + WEL_;
  short* k16  = q16 + rowelems;
  short* vt   = k16 + rowelems;
  short* qh   = vt + rowelems;
  short* kh   = qh + rowelems;
  short* att16 = q16;                                 // reuse after rms_rope(q)
  float* out = (float*)d_out;

  f2h5_k<<<7680, 256, 0, stream>>>(x, wq, wk, wv, wo, x16, w16, wo16);

  gemm_qkv16_k<<<1152, 256, 0, stream>>>(x16, w16, bq, bk, bv, q16, k16, vt);

  rms_rope_qk_k<<<dim3(M_, 2), 256, 0, stream>>>(
      q16, k16, nq, nk, cf, sf, ch, sh, cw, sw, qh, kh);

  attn_mfma5_k<<<768, 256, 0, stream>>>(qh, kh, vt, seq_lens, att16);

  gemm_out64_k<<<768, 256, 0, stream>>>(att16, wo16, bo, out);
}

// Round 13
// 246.216 us; speedup vs baseline: 1.0849x; 1.0849x over previous
//
#include <hip/hip_runtime.h>
#include <hip/hip_bf16.h>
#include <math.h>

#define DIM_  1536
#define NH_   12
#define HD_   128
#define S_    2048
#define B_    2
#define M_    (B_*S_)       /* 4096 rows */
#define WEL_  (DIM_*DIM_)   /* 2359296 */

typedef __attribute__((ext_vector_type(8))) _Float16 f16x8;
typedef __attribute__((ext_vector_type(4))) short short4v;
typedef __attribute__((ext_vector_type(8))) short short8v;
typedef __attribute__((ext_vector_type(4))) float f32x4;

#define SSCALE_LOG2E (0.08838834764831845f * 1.4426950408889634f)

static __device__ __forceinline__ short f2h(float f) {
  union { _Float16 h; short s; } u;
  u.h = (_Float16)f;
  return u.s;
}

static __device__ __forceinline__ unsigned pk2h(float a, float b) {
  typedef __attribute__((ext_vector_type(2))) __fp16 fp16x2;
  union { fp16x2 v; unsigned u; } u2;
  u2.v = __builtin_amdgcn_cvt_pkrtz(a, b);
  return u2.u;
}

// ---------------------------------------------------------------------------
// Fused convert: x + wq/wk/wv/wo -> fp16. 1966080 chunks of 8.
// ---------------------------------------------------------------------------
__global__ __launch_bounds__(256) void f2h5_k(
    const float* __restrict__ x, const float* __restrict__ wq,
    const float* __restrict__ wk, const float* __restrict__ wv,
    const float* __restrict__ wo,
    short* __restrict__ x16, short* __restrict__ w16, short* __restrict__ wo16)
{
  int i = blockIdx.x * 256 + threadIdx.x;
  const float* src; short* dst; int j;
  if (i < 786432)       { src = x;  dst = x16;            j = i; }
  else if (i < 1081344) { src = wq; dst = w16;            j = i - 786432; }
  else if (i < 1376256) { src = wk; dst = w16 + WEL_;     j = i - 1081344; }
  else if (i < 1671168) { src = wv; dst = w16 + 2 * WEL_; j = i - 1376256; }
  else                  { src = wo; dst = wo16;           j = i - 1671168; }
  const float4* p = (const float4*)src + (size_t)j * 2;
  float4 a = p[0], b = p[1];
  short8v o;
  o[0] = f2h(a.x); o[1] = f2h(a.y); o[2] = f2h(a.z); o[3] = f2h(a.w);
  o[4] = f2h(b.x); o[5] = f2h(b.y); o[6] = f2h(b.z); o[7] = f2h(b.w);
  *((short8v*)dst + j) = o;
}

// ---------------------------------------------------------------------------
// MFMA fp16 GEMM core (R10 config): double-buffered LDS, one barrier/K-step,
// frag-reads -> STAGE(next) -> MFMA -> barrier. 128x128 tile, BK=32, 4 waves.
// MODE 0: fp16 row-major out. MODE 2: transposed V out vt[bh*HD+d][s].
// ---------------------------------------------------------------------------
template<int MODE>
static __device__ __forceinline__ void gemm16_core(
    const short* __restrict__ A16, const short* __restrict__ W16,
    const float* __restrict__ bias, short* __restrict__ Outp,
    int m0, int n0, char* __restrict__ Ab, char* __restrict__ Bb)
{
  const int tid = threadIdx.x;
  const int l  = tid & 63, w = tid >> 6;
  const int wr = w >> 1, wc = w & 1;
  const int lc = l & 15, lg = l >> 4;

  f32x4 acc[4][4] = {};

  const int rs  = w * 16 + (l >> 2);
  const int gsl = ((l & 3) ^ ((rs >> 1) & 3)) * 8;
  const short* gA0 = A16 + (size_t)(m0 + rs) * DIM_ + gsl;
  const short* gA1 = A16 + (size_t)(m0 + 64 + rs) * DIM_ + gsl;
  const short* gB0 = W16 + (size_t)(n0 + rs) * DIM_ + gsl;
  const short* gB1 = W16 + (size_t)(n0 + 64 + rs) * DIM_ + gsl;

#define GSTAGE(buf, k0)                                                        \
  {                                                                            \
    __builtin_amdgcn_global_load_lds(                                          \
        (const __attribute__((address_space(1))) unsigned*)(gA0 + (k0)),       \
        (__attribute__((address_space(3))) unsigned*)(Ab + (buf) * 8192 + w * 1024), 16, 0, 0); \
    __builtin_amdgcn_global_load_lds(                                          \
        (const __attribute__((address_space(1))) unsigned*)(gA1 + (k0)),       \
        (__attribute__((address_space(3))) unsigned*)(Ab + (buf) * 8192 + 4096 + w * 1024), 16, 0, 0); \
    __builtin_amdgcn_global_load_lds(                                          \
        (const __attribute__((address_space(1))) unsigned*)(gB0 + (k0)),       \
        (__attribute__((address_space(3))) unsigned*)(Bb + (buf) * 8192 + w * 1024), 16, 0, 0); \
    __builtin_amdgcn_global_load_lds(                                          \
        (const __attribute__((address_space(1))) unsigned*)(gB1 + (k0)),       \
        (__attribute__((address_space(3))) unsigned*)(Bb + (buf) * 8192 + 4096 + w * 1024), 16, 0, 0); \
  }

  GSTAGE(0, 0);
  __syncthreads();                       // buf0 ready
  int cur = 0;
  for (int k0 = 0; k0 < DIM_; k0 += 32) {
    const char* Ac = Ab + cur * 8192;
    const char* Bc = Bb + cur * 8192;
    f16x8 af[4], bf[4];
#pragma unroll
    for (int mt = 0; mt < 4; ++mt) {
      int ar = wr * 64 + mt * 16 + lc;
      af[mt] = *(const f16x8*)(Ac + ar * 64 + ((lg ^ ((ar >> 1) & 3)) << 4));
    }
#pragma unroll
    for (int nt = 0; nt < 4; ++nt) {
      int br = wc * 64 + nt * 16 + lc;
      bf[nt] = *(const f16x8*)(Bc + br * 64 + ((lg ^ ((br >> 1) & 3)) << 4));
    }
    if (k0 + 32 < DIM_) GSTAGE(cur ^ 1, k0 + 32);   // drain overlaps MFMA
    __builtin_amdgcn_s_setprio(1);
#pragma unroll
    for (int mt = 0; mt < 4; ++mt)
#pragma unroll
      for (int nt = 0; nt < 4; ++nt)
        acc[mt][nt] = __builtin_amdgcn_mfma_f32_16x16x32_f16(af[mt], bf[nt], acc[mt][nt], 0, 0, 0);
    __builtin_amdgcn_s_setprio(0);
    __syncthreads();                     // next buf ready; cur reads all done
    cur ^= 1;
  }
#undef GSTAGE

  if (MODE == 0) {
#pragma unroll
    for (int nt = 0; nt < 4; ++nt) {
      int col = n0 + wc * 64 + nt * 16 + lc;
      float bb = bias[col];
#pragma unroll
      for (int mt = 0; mt < 4; ++mt) {
#pragma unroll
        for (int r = 0; r < 4; ++r) {
          int rowm = m0 + wr * 64 + mt * 16 + lg * 4 + r;
          Outp[(size_t)rowm * DIM_ + col] = f2h(acc[mt][nt][r] + bb);
        }
      }
    }
  } else {
#pragma unroll
    for (int nt = 0; nt < 4; ++nt) {
      int colg = n0 + wc * 64 + nt * 16 + lc;
      int h = colg >> 7, d = colg & 127;
      float bb = bias[colg];
#pragma unroll
      for (int mt = 0; mt < 4; ++mt) {
        int rowg = m0 + wr * 64 + mt * 16 + lg * 4;
        int b = rowg >> 11, s = rowg & (S_ - 1);
        short4v o4;
#pragma unroll
        for (int r = 0; r < 4; ++r) o4[r] = f2h(acc[mt][nt][r] + bb);
        *(short4v*)(Outp + ((size_t)((b * NH_ + h) * HD_ + d)) * S_ + s) = o4;
      }
    }
  }
}

__global__ __launch_bounds__(256) void gemm_qkv16_k(
    const short* __restrict__ x16, const short* __restrict__ w16,
    const float* __restrict__ bq, const float* __restrict__ bk,
    const float* __restrict__ bv,
    short* __restrict__ q16, short* __restrict__ k16, short* __restrict__ vt)
{
  __shared__ __align__(16) char Ab[2][8192];
  __shared__ __align__(16) char Bb[2][8192];
  const int z = blockIdx.z;
  if (z == 2)
    gemm16_core<2>(x16, w16 + 2 * (size_t)WEL_, bv, vt,
                   blockIdx.y * 128, blockIdx.x * 128, &Ab[0][0], &Bb[0][0]);
  else
    gemm16_core<0>(x16, w16 + (size_t)z * WEL_, z ? bk : bq, z ? k16 : q16,
                   blockIdx.y * 128, blockIdx.x * 128, &Ab[0][0], &Bb[0][0]);
}

// ---------------------------------------------------------------------------
// gemm_out: 128x64 tile, dbuf, one barrier/step, fp32 out. (R10 config)
// ---------------------------------------------------------------------------
__global__ __launch_bounds__(256) void gemm_out64_k(
    const short* __restrict__ att16, const short* __restrict__ wo16,
    const float* __restrict__ bo, float* __restrict__ out)
{
  __shared__ __align__(16) char Ab[2][8192];
  __shared__ __align__(16) char Bb[2][4096];
  const int m0 = blockIdx.y * 128, n0 = blockIdx.x * 64;
  const int tid = threadIdx.x;
  const int l  = tid & 63, w = tid >> 6;
  const int lc = l & 15, lg = l >> 4;

  f32x4 acc[2][4] = {};

  const int rsA = w * 32 + (l >> 2);
  const int rsB = w * 16 + (l >> 2);
  const int gslA = ((l & 3) ^ ((rsA >> 1) & 3)) * 8;
  const int gslB = ((l & 3) ^ ((rsB >> 1) & 3)) * 8;
  const short* gA0 = att16 + (size_t)(m0 + rsA) * DIM_ + gslA;
  const short* gA1 = att16 + (size_t)(m0 + 16 + rsA) * DIM_ + gslA;
  const short* gB0 = wo16 + (size_t)(n0 + rsB) * DIM_ + gslB;

#define GSTAGE(buf, k0)                                                        \
  {                                                                            \
    __builtin_amdgcn_global_load_lds(                                          \
        (const __attribute__((address_space(1))) unsigned*)(gA0 + (k0)),       \
        (__attribute__((address_space(3))) unsigned*)(&Ab[buf][0] + w * 2048), 16, 0, 0); \
    __builtin_amdgcn_global_load_lds(                                          \
        (const __attribute__((address_space(1))) unsigned*)(gA1 + (k0)),       \
        (__attribute__((address_space(3))) unsigned*)(&Ab[buf][0] + w * 2048 + 1024), 16, 0, 0); \
    __builtin_amdgcn_global_load_lds(                                          \
        (const __attribute__((address_space(1))) unsigned*)(gB0 + (k0)),       \
        (__attribute__((address_space(3))) unsigned*)(&Bb[buf][0] + w * 1024), 16, 0, 0); \
  }

  GSTAGE(0, 0);
  __syncthreads();
  int cur = 0;
  for (int k0 = 0; k0 < DIM_; k0 += 32) {
    const char* Ac = &Ab[cur][0];
    const char* Bc = &Bb[cur][0];
    f16x8 af[2], bf[4];
#pragma unroll
    for (int mt = 0; mt < 2; ++mt) {
      int ar = w * 32 + mt * 16 + lc;
      af[mt] = *(const f16x8*)(Ac + ar * 64 + ((lg ^ ((ar >> 1) & 3)) << 4));
    }
#pragma unroll
    for (int nt = 0; nt < 4; ++nt) {
      int br = nt * 16 + lc;
      bf[nt] = *(const f16x8*)(Bc + br * 64 + ((lg ^ ((br >> 1) & 3)) << 4));
    }
    if (k0 + 32 < DIM_) GSTAGE(cur ^ 1, k0 + 32);
    __builtin_amdgcn_s_setprio(1);
#pragma unroll
    for (int mt = 0; mt < 2; ++mt)
#pragma unroll
      for (int nt = 0; nt < 4; ++nt)
        acc[mt][nt] = __builtin_amdgcn_mfma_f32_16x16x32_f16(af[mt], bf[nt], acc[mt][nt], 0, 0, 0);
    __builtin_amdgcn_s_setprio(0);
    __syncthreads();
    cur ^= 1;
  }
#undef GSTAGE

#pragma unroll
  for (int nt = 0; nt < 4; ++nt) {
    int col = n0 + nt * 16 + lc;
    float bb = bo[col];
#pragma unroll
    for (int mt = 0; mt < 2; ++mt) {
#pragma unroll
      for (int r = 0; r < 4; ++r) {
        int rowm = m0 + w * 32 + mt * 16 + lg * 4 + r;
        out[(size_t)rowm * DIM_ + col] = acc[mt][nt][r] + bb;
      }
    }
  }
}

// ---------------------------------------------------------------------------
// RMSNorm + grid RoPE, fp16 in -> fp16 head-major; q (z=0) and k (z=1) in one
// dispatch; q gets sscale*log2e folded in.
// ---------------------------------------------------------------------------
__global__ __launch_bounds__(256) void rms_rope_qk_k(
    const short* __restrict__ q16, const short* __restrict__ k16,
    const float* __restrict__ nq, const float* __restrict__ nk,
    const float* __restrict__ cf, const float* __restrict__ sf,
    const float* __restrict__ ch, const float* __restrict__ sh,
    const float* __restrict__ cw, const float* __restrict__ sw,
    short* __restrict__ qh, short* __restrict__ kh)
{
  const int z   = blockIdx.y;
  const short* t = z ? k16 : q16;
  const float* w = z ? nk : nq;
  short* outb   = z ? kh : qh;
  const float qsc0 = z ? 1.0f : SSCALE_LOG2E;

  const int row = blockIdx.x;
  const int b   = row >> 11;
  const int s   = row & (S_ - 1);
  const _Float16* rp = (const _Float16*)(t + (size_t)row * DIM_);

  float ss = 0.f;
  for (int i = threadIdx.x; i < DIM_; i += 256) {
    float v2 = (float)rp[i]; ss += v2 * v2;
  }
#pragma unroll
  for (int off = 32; off > 0; off >>= 1) ss += __shfl_down(ss, off);
  __shared__ float red[4];
  if ((threadIdx.x & 63) == 0) red[threadIdx.x >> 6] = ss;
  __syncthreads();
  float scale = rsqrtf((red[0] + red[1] + red[2] + red[3]) * (1.f / DIM_) + 1e-6f) * qsc0;

  const int fi = s >> 8;
  const int hi = (s >> 4) & 15;
  const int wi = s & 15;

  for (int p = threadIdx.x; p < NH_ * 64; p += 256) {
    int n = p >> 6, c = p & 63;
    float co, si;
    if (c < 22)      { co = cf[fi * 22 + c];        si = sf[fi * 22 + c]; }
    else if (c < 43) { co = ch[hi * 21 + (c - 22)]; si = sh[hi * 21 + (c - 22)]; }
    else             { co = cw[wi * 21 + (c - 43)]; si = sw[wi * 21 + (c - 43)]; }
    int d0 = n * HD_ + 2 * c;
    float xr = (float)rp[d0]     * scale * w[d0];
    float xi = (float)rp[d0 + 1] * scale * w[d0 + 1];
    float rr = xr * co - xi * si;
    float ri = xr * si + xi * co;
    *(unsigned int*)(outb + (((size_t)(b * NH_ + n) * S_ + s) * HD_ + 2 * c)) = pk2h(rr, ri);
  }
}

// ---------------------------------------------------------------------------
// fp16 MFMA flash attention v5 (R10 config: plain 2-D grid, no swizzle).
// 4 waves x 16 queries, LDS-shared K/V, split-barrier pipeline, in-lane
// log2-domain softmax, defer-max, hoisted pre-swizzled global_load_lds.
// ---------------------------------------------------------------------------
__global__ __launch_bounds__(256) void attn_mfma5_k(
    const short* __restrict__ qb, const short* __restrict__ kb,
    const short* __restrict__ vtb, const int* __restrict__ seq_lens,
    short* __restrict__ o16)
{
  const int bh = blockIdx.y;
  const int b  = bh / NH_;
  const int h  = bh - b * NH_;
  const int q0 = blockIdx.x << 6;
  const int kvlen = seq_lens[b];
  const int tid  = threadIdx.x;
  const int wid  = tid >> 6;
  const int lane = tid & 63;
  const int lg   = lane >> 4;
  const int lc   = lane & 15;
  const int xo   = (lc & 7) << 4;

  __shared__ __align__(16) char Kt[16384];
  __shared__ __align__(16) char Vt[16384];
  __shared__ __align__(16) char Pt[4][2048];

  f16x8 bq[4];
  {
    const size_t base = ((size_t)bh * S_ + q0 + wid * 16 + lc) * HD_;
#pragma unroll
    for (int dc = 0; dc < 4; ++dc)
      bq[dc] = *(const f16x8*)(qb + base + dc * 32 + lg * 8);
  }

  const short* kgA = kb + ((size_t)bh * S_ + wid * 16 + lg) * HD_
                        + ((lc * 8) ^ (lg << 3));
  const short* kgB = kb + ((size_t)bh * S_ + wid * 16 + 4 + lg) * HD_
                        + ((lc * 8) ^ ((lg ^ 4) << 3));
  const short* vg  = vtb + ((size_t)bh * HD_ + wid * 32 + (lane >> 3)) * S_
                         + (((lane & 7) * 8) ^ ((lane >> 3) << 3));

#define STAGE_K()                                                              \
  {                                                                            \
    _Pragma("unroll")                                                          \
    for (int j = 0; j < 4; ++j) {                                              \
      const short* g = (j & 1) ? (kgB + ((j - 1) >> 1) * (8 * HD_))            \
                               : (kgA + (j >> 1) * (8 * HD_));                 \
      __builtin_amdgcn_global_load_lds(                                        \
          (const __attribute__((address_space(1))) unsigned*)g,                \
          (__attribute__((address_space(3))) unsigned*)(Kt + (wid * 16 + j * 4) * 256), \
          16, 0, 0);                                                           \
    }                                                                          \
  }
#define STAGE_V()                                                              \
  {                                                                            \
    _Pragma("unroll")                                                          \
    for (int j = 0; j < 4; ++j) {                                              \
      __builtin_amdgcn_global_load_lds(                                        \
          (const __attribute__((address_space(1))) unsigned*)(vg + j * 8 * S_),\
          (__attribute__((address_space(3))) unsigned*)(Vt + (wid * 32 + j * 8) * 128), \
          16, 0, 0);                                                           \
    }                                                                          \
  }

  f32x4 oacc[8] = {};
  float m = -3.0e38f, l = 0.f;

  const int nt = kvlen >> 6;

  STAGE_K();
  kgA += 64 * HD_; kgB += 64 * HD_;
  __syncthreads();

  for (int ti = 0; ti < nt; ++ti) {
    STAGE_V();
    vg += 64;

    f32x4 s[4];
    __builtin_amdgcn_s_setprio(1);
#pragma unroll
    for (int kt = 0; kt < 4; ++kt) {
      f32x4 a = {0.f, 0.f, 0.f, 0.f};
      const char* kr = Kt + (kt * 16 + lc) * 256;
#pragma unroll
      for (int dc = 0; dc < 4; ++dc) {
        f16x8 kf = *(const f16x8*)(kr + ((dc * 64 + lg * 16) ^ xo));
        a = __builtin_amdgcn_mfma_f32_16x16x32_f16(kf, bq[dc], a, 0, 0, 0);
      }
      s[kt] = a;
    }
    __builtin_amdgcn_s_setprio(0);

    float t0 = -3.0e38f;
#pragma unroll
    for (int kt = 0; kt < 4; ++kt)
#pragma unroll
      for (int r = 0; r < 4; ++r) t0 = fmaxf(t0, s[kt][r]);
    t0 = fmaxf(t0, __shfl_xor(t0, 16));
    t0 = fmaxf(t0, __shfl_xor(t0, 32));

    if (__any(t0 > m + 8.f)) {
      float mn = fmaxf(m, t0);
      float a  = exp2f(m - mn);
      m = mn; l *= a;
#pragma unroll
      for (int r = 0; r < 4; ++r) {
        float ar = __shfl(a, 4 * lg + r);
#pragma unroll
        for (int n = 0; n < 8; ++n) oacc[n][r] *= ar;
      }
    }
    float ls = 0.f;
#pragma unroll
    for (int kt = 0; kt < 4; ++kt)
#pragma unroll
      for (int r = 0; r < 4; ++r) {
        float p = exp2f(s[kt][r] - m); s[kt][r] = p; ls += p;
      }
    ls += __shfl_xor(ls, 16);
    ls += __shfl_xor(ls, 32);
    l += ls;

    {
      char* pr = Pt[wid] + lc * 128;
#pragma unroll
      for (int kt = 0; kt < 4; ++kt) {
#pragma unroll
        for (int rr = 0; rr < 2; ++rr) {
          unsigned u = pk2h(s[kt][2 * rr], s[kt][2 * rr + 1]);
          int off = (kt * 32 + lg * 8 + rr * 4) ^ xo;
          *(unsigned*)(pr + off) = u;
        }
      }
    }

    __syncthreads();

    if (ti + 1 < nt) {
      STAGE_K();
      kgA += 64 * HD_; kgB += 64 * HD_;
    }

    __builtin_amdgcn_s_setprio(1);
#pragma unroll
    for (int kc = 0; kc < 2; ++kc) {
      f16x8 pa = *(const f16x8*)(Pt[wid] + lc * 128 + ((kc * 64 + lg * 16) ^ xo));
#pragma unroll
      for (int n = 0; n < 8; ++n) {
        f16x8 vf = *(const f16x8*)(Vt + (n * 16 + lc) * 128 + ((kc * 64 + lg * 16) ^ xo));
        oacc[n] = __builtin_amdgcn_mfma_f32_16x16x32_f16(pa, vf, oacc[n], 0, 0, 0);
      }
    }
    __builtin_amdgcn_s_setprio(0);

    __syncthreads();
  }

#pragma unroll
  for (int r = 0; r < 4; ++r) {
    float li = 1.f / __shfl(l, 4 * lg + r);
    int qrow = q0 + wid * 16 + 4 * lg + r;
#pragma unroll
    for (int n = 0; n < 8; ++n)
      o16[((size_t)(b * S_ + qrow) * NH_ + h) * HD_ + n * 16 + lc] = f2h(oacc[n][r] * li);
  }
#undef STAGE_K
#undef STAGE_V
}

// ---------------------------------------------------------------------------
// Workspace (94.4 MB, all fp16):
//  x16 | w16(3) | wo16 | q16(->att16) | k16 | vt | qh | kh
// ---------------------------------------------------------------------------
extern "C" void kernel_launch(void* const* d_in, const int* in_sizes, int n_in,
                              void* d_out, int out_size, void* d_ws, size_t ws_size,
                              hipStream_t stream) {
  const float* x        = (const float*)d_in[0];
  const int*   seq_lens = (const int*)d_in[1];
  const float* wq = (const float*)d_in[5];
  const float* bq = (const float*)d_in[6];
  const float* wk = (const float*)d_in[7];
  const float* bk = (const float*)d_in[8];
  const float* wv = (const float*)d_in[9];
  const float* bv = (const float*)d_in[10];
  const float* wo = (const float*)d_in[11];
  const float* bo = (const float*)d_in[12];
  const float* nq = (const float*)d_in[13];
  const float* nk = (const float*)d_in[14];
  const float* cf = (const float*)d_in[15];
  const float* sf = (const float*)d_in[16];
  const float* ch = (const float*)d_in[17];
  const float* sh = (const float*)d_in[18];
  const float* cw = (const float*)d_in[19];
  const float* sw = (const float*)d_in[20];

  const size_t rowelems = (size_t)M_ * DIM_;          // 6291456
  short* x16  = (short*)d_ws;
  short* w16  = x16 + rowelems;                       // 3*WEL_
  short* wo16 = w16 + 3 * (size_t)WEL_;
  short* q16  = wo16 + WEL_;
  short* k16  = q16 + rowelems;
  short* vt   = k16 + rowelems;
  short* qh   = vt + rowelems;
  short* kh   = qh + rowelems;
  short* att16 = q16;                                 // reuse after rms_rope(q)
  float* out = (float*)d_out;

  f2h5_k<<<7680, 256, 0, stream>>>(x, wq, wk, wv, wo, x16, w16, wo16);

  gemm_qkv16_k<<<dim3(DIM_ / 128, M_ / 128, 3), 256, 0, stream>>>(
      x16, w16, bq, bk, bv, q16, k16, vt);

  rms_rope_qk_k<<<dim3(M_, 2), 256, 0, stream>>>(
      q16, k16, nq, nk, cf, sf, ch, sh, cw, sw, qh, kh);

  attn_mfma5_k<<<dim3(S_ / 64, B_ * NH_), 256, 0, stream>>>(qh, kh, vt, seq_lens, att16);

  gemm_out64_k<<<dim3(DIM_ / 64, M_ / 128), 256, 0, stream>>>(att16, wo16, bo, out);
}